// Round 11
// baseline (212.344 us; speedup 1.0000x reference)
//
#include <hip/hip_runtime.h>

#define N_ITEMS 65536

// ---------------- Kernel 1: qpart[z] = x @ W (K-chunk 256 per z) + pack ------
// 64x64 tile, ONE WAVE per block, 8x8 micro per lane. Grid (16,16,5):
// z<4 = K-split GEMM -> 1024 independent single-wave blocks = 4/CU, so
// staging stalls of one block overlap compute of the other three (m114) —
// the old 256-block config was 1 block/CU with all 4 waves chained to one
// barrier (fully exposed latency). Fragment reads are 8-lane broadcasts
// (free); A-scatter staging lands exactly 2 lanes/bank (free, m136).
// z==4 plane: pack key_codes -> poffs/pcodes (256 blocks x 64 thr x 4 items).
__launch_bounds__(64)
__global__ void gemm_q_kernel(const float* __restrict__ A,
                              const float* __restrict__ W,
                              float* __restrict__ qpart,
                              const int* __restrict__ key_codes,
                              unsigned long long* __restrict__ pcodes,
                              uint4* __restrict__ poffs) {
  if (blockIdx.z == 4) {
    const int g0 = (((int)blockIdx.y * 16 + (int)blockIdx.x) * 64 + (int)threadIdx.x) * 4;
#pragma unroll
    for (int t = 0; t < 4; t++) {
      const int gid = g0 + t;
      unsigned long long p = 0ull;
      unsigned h[8];
#pragma unroll
      for (int j = 0; j < 8; j++) {
        const unsigned c = (unsigned)key_codes[gid * 8 + j] & 255u;
        p |= (unsigned long long)c << (8 * j);
        h[j] = ((c >> 1) << 7) | ((c & 1u) << 2);  // scan2r seg-local byte off
      }
      pcodes[gid] = p;
      poffs[gid] = make_uint4(h[0] | (h[1] << 16), h[2] | (h[3] << 16),
                              h[4] | (h[5] << 16), h[6] | (h[7] << 16));
    }
    return;
  }

  __shared__ float As[16][68];  // [kk][row], +4 pad
  __shared__ float Bs[16][68];  // [kk][col]
  const int tid = threadIdx.x;            // 0..63, one wave
  const int tx = tid & 7, ty = tid >> 3;  // 8 col-groups x 8 row-groups
  const int rb = blockIdx.y * 64, cb = blockIdx.x * 64;
  const int kz = blockIdx.z * 256;

  // staging maps: A 64 rows x 16 k (4 float4/thread), B 16 kk x 64 cols (4/thread)
  float4 va[4], vb[4];
#pragma unroll
  for (int j = 0; j < 4; j++) {
    const int e = tid + (j << 6);
    va[j] = *(const float4*)&A[(rb + (e >> 2)) * 1024 + kz + ((e & 3) << 2)];
    vb[j] = *(const float4*)&W[(kz + (e >> 4)) * 1024 + cb + ((e & 15) << 2)];
  }

  float acc[8][8] = {};
  for (int k0 = 0; k0 < 256; k0 += 16) {
#pragma unroll
    for (int j = 0; j < 4; j++) {
      const int e = tid + (j << 6);
      const int row = e >> 2, c4 = (e & 3) << 2;
      As[c4 + 0][row] = va[j].x; As[c4 + 1][row] = va[j].y;
      As[c4 + 2][row] = va[j].z; As[c4 + 3][row] = va[j].w;
      *(float4*)&Bs[e >> 4][(e & 15) << 2] = vb[j];
    }
    __syncthreads();
    if (k0 + 16 < 256) {  // register double-buffer next K-tile
#pragma unroll
      for (int j = 0; j < 4; j++) {
        const int e = tid + (j << 6);
        va[j] = *(const float4*)&A[(rb + (e >> 2)) * 1024 + kz + k0 + 16 + ((e & 3) << 2)];
        vb[j] = *(const float4*)&W[(kz + k0 + 16 + (e >> 4)) * 1024 + cb + ((e & 15) << 2)];
      }
    }
#pragma unroll
    for (int kk = 0; kk < 16; kk++) {
      const float4 a0 = *(const float4*)&As[kk][ty << 2];
      const float4 a1 = *(const float4*)&As[kk][32 + (ty << 2)];
      const float4 b0 = *(const float4*)&Bs[kk][tx << 2];
      const float4 b1 = *(const float4*)&Bs[kk][32 + (tx << 2)];
      const float ar8[8] = {a0.x, a0.y, a0.z, a0.w, a1.x, a1.y, a1.z, a1.w};
      const float br8[8] = {b0.x, b0.y, b0.z, b0.w, b1.x, b1.y, b1.z, b1.w};
#pragma unroll
      for (int r = 0; r < 8; r++)
#pragma unroll
        for (int c = 0; c < 8; c++)
          acc[r][c] = fmaf(ar8[r], br8[c], acc[r][c]);
    }
    __syncthreads();
  }
  float* outp = qpart + blockIdx.z * 1048576;
#pragma unroll
  for (int rh = 0; rh < 2; rh++)
#pragma unroll
    for (int r = 0; r < 4; r++) {
      const int row = rb + rh * 32 + (ty << 2) + r;
      const int ri = rh * 4 + r;
      *(float4*)&outp[row * 1024 + cb + (tx << 2)] =
          make_float4(acc[ri][0], acc[ri][1], acc[ri][2], acc[ri][3]);
      *(float4*)&outp[row * 1024 + cb + 32 + (tx << 2)] =
          make_float4(acc[ri][4], acc[ri][5], acc[ri][6], acc[ri][7]);
    }
}

// ---------------- Kernel 2: lut + in-register qsq/csq ----------
__launch_bounds__(256)
__global__ void lut_kernel(const float* __restrict__ qpart,
                           const float* __restrict__ kcb,
                           float* __restrict__ lut) {
  __shared__ float As[32][68];
  __shared__ float Bs[32][68];
  const int tid = threadIdx.x;
  const int tx = tid & 15, ty = tid >> 4;
  const int m = blockIdx.z;
  const int rb = blockIdx.y * 64;
  const int cb0 = blockIdx.x * 64;
  float acc[4][4] = {};
  float qa[4] = {}, cs[4] = {};
  for (int k0 = 0; k0 < 128; k0 += 32) {
#pragma unroll
    for (int l = 0; l < 2; l++) {
      const int e = tid + l * 256;
      const int row = e >> 3, c4 = (e & 7) << 2;
      const int qidx = (rb + row) * 1024 + m * 128 + k0 + c4;
      const float4 p0 = *(const float4*)&qpart[qidx];
      const float4 p1 = *(const float4*)&qpart[qidx + 1048576];
      const float4 p2 = *(const float4*)&qpart[qidx + 2097152];
      const float4 p3 = *(const float4*)&qpart[qidx + 3145728];
      const float4 va = make_float4(p0.x + p1.x + p2.x + p3.x,
                                    p0.y + p1.y + p2.y + p3.y,
                                    p0.z + p1.z + p2.z + p3.z,
                                    p0.w + p1.w + p2.w + p3.w);
      As[c4 + 0][row] = va.x; As[c4 + 1][row] = va.y;
      As[c4 + 2][row] = va.z; As[c4 + 3][row] = va.w;
      const float4 vb = *(const float4*)&kcb[(m * 256 + cb0 + row) * 128 + k0 + c4];
      Bs[c4 + 0][row] = vb.x; Bs[c4 + 1][row] = vb.y;
      Bs[c4 + 2][row] = vb.z; Bs[c4 + 3][row] = vb.w;
    }
    __syncthreads();
#pragma unroll
    for (int kk = 0; kk < 32; kk++) {
      const float4 a = *(const float4*)&As[kk][ty << 2];
      const float4 b = *(const float4*)&Bs[kk][tx << 2];
      const float ar[4] = {a.x, a.y, a.z, a.w};
      const float br[4] = {b.x, b.y, b.z, b.w};
#pragma unroll
      for (int r = 0; r < 4; r++)
#pragma unroll
        for (int c = 0; c < 4; c++)
          acc[r][c] = fmaf(ar[r], br[c], acc[r][c]);
#pragma unroll
      for (int r = 0; r < 4; r++) qa[r] = fmaf(ar[r], ar[r], qa[r]);
#pragma unroll
      for (int c = 0; c < 4; c++) cs[c] = fmaf(br[c], br[c], cs[c]);
    }
    __syncthreads();
  }
#pragma unroll
  for (int r = 0; r < 4; r++) {
    const int row = rb + (ty << 2) + r;
    const int col = cb0 + (tx << 2);
    float4 v;
    v.x = qa[r] + cs[0] - 2.0f * acc[r][0];
    v.y = qa[r] + cs[1] - 2.0f * acc[r][1];
    v.z = qa[r] + cs[2] - 2.0f * acc[r][2];
    v.w = qa[r] + cs[3] - 2.0f * acc[r][3];
    *(float4*)&lut[row * 2048 + m * 256 + col] = v;
  }
}

// ---------------- Kernel 3a: 2-ROW ADC scan (verified 65.9us r10) ------------
extern __shared__ char dyn_lds[];

__launch_bounds__(1024)
__global__ void scan2r_kernel(const float* __restrict__ lut,
                              const uint4* __restrict__ poffs,
                              unsigned* __restrict__ cand_d,
                              unsigned short* __restrict__ cand_n) {
  char* repb = dyn_lds;                              // 131072 B table
  unsigned* repw = (unsigned*)dyn_lds;
  short* temps = (short*)(dyn_lds + 131072);         // 2048 x 2 i16 (8 KB)
  unsigned* tempw = (unsigned*)(dyn_lds + 131072);
  const int tid = threadIdx.x;
  const int g = blockIdx.x;

  {
    const int w = tid >> 6, lane = tid & 63;
    const int rr = w & 1, seg = w >> 1;
    const int row = (g << 1) + rr;
    const int e0 = seg * 256 + lane * 4;
    const float4 v4 = *(const float4*)&lut[row * 2048 + e0];
    float s4 = v4.x + v4.y + v4.z + v4.w;
#pragma unroll
    for (int off = 32; off > 0; off >>= 1) s4 += __shfl_xor(s4, off);
    const float mean = s4 * (1.0f / 256.0f);
    const float vals[4] = {v4.x, v4.y, v4.z, v4.w};
#pragma unroll
    for (int k = 0; k < 4; k++) {
      float f = (vals[k] - mean) * 64.0f;
      f = fmaxf(fminf(f, 32000.0f), -32000.0f);
      temps[(e0 + k) * 2 + rr] = (short)(int)rintf(f);
    }
  }
  __syncthreads();

  {
    const int lane = tid & 63;
    const unsigned v0 = tempw[tid * 2];
    const unsigned v1 = tempw[tid * 2 + 1];
    const int Dbase = tid * 32;
#pragma unroll
    for (int k = 0; k < 16; k++) {
      const int r = (k + lane) & 15;
      repw[Dbase + 2 * r] = v0;
      repw[Dbase + 1 + 2 * r] = v1;
    }
  }
  __syncthreads();

  const int r = tid & 15;
  const char* base0 = repb + (r << 3);
  const char* base1 = repb + 65536 + (r << 3);
  int d0a = 0x7FFFFFFF, d1a = 0x7FFFFFFF, i0a = 0, i1a = 0;
  int d0b = 0x7FFFFFFF, d1b = 0x7FFFFFFF, i0b = 0, i1b = 0;

  uint4 oc = poffs[tid];
  uint4 nc = poffs[tid + 1024];
  for (int it = 0; it < 64; it++) {
    const int n = tid + (it << 10);
    uint4 nn2 = nc;
    if (it < 62) nn2 = poffs[n + 2048];
    unsigned wv;
    int s0, s1;
    wv = *(const unsigned*)(base0 + (oc.x & 0xFFFFu));
    s0 = (int)(short)wv; s1 = ((int)wv) >> 16;
#define LK(B, HV, OFS) { wv = *(const unsigned*)((B) + (HV) + (OFS)); \
    s0 += (int)(short)wv; s1 += ((int)wv) >> 16; }
    LK(base0, oc.x >> 16, 16384)
    LK(base0, oc.y & 0xFFFFu, 32768)
    LK(base0, oc.y >> 16, 49152)
    LK(base1, oc.z & 0xFFFFu, 0)
    LK(base1, oc.z >> 16, 16384)
    LK(base1, oc.w & 0xFFFFu, 32768)
    LK(base1, oc.w >> 16, 49152)
#undef LK
    if (s0 < d1a) {
      if (s0 < d0a) { d1a = d0a; i1a = i0a; d0a = s0; i0a = n; }
      else          { d1a = s0; i1a = n; }
    }
    if (s1 < d1b) {
      if (s1 < d0b) { d1b = d0b; i1b = i0b; d0b = s1; i0b = n; }
      else          { d1b = s1; i1b = n; }
    }
    oc = nc; nc = nn2;
  }

  {
    const int ba = (g << 1) * 2048 + tid * 2;
    *(uint2*)&cand_d[ba] = make_uint2((unsigned)(d0a + 0x40000000),
                                      (unsigned)(d1a + 0x40000000));
    *(unsigned*)&cand_n[ba] = (unsigned)i0a | ((unsigned)i1a << 16);
    const int bb = ((g << 1) + 1) * 2048 + tid * 2;
    *(uint2*)&cand_d[bb] = make_uint2((unsigned)(d0b + 0x40000000),
                                      (unsigned)(d1b + 0x40000000));
    *(unsigned*)&cand_n[bb] = (unsigned)i0b | ((unsigned)i1b << 16);
  }
}

// ---------------- Kernel 3b: fallback 64KB scan (verified) ----------------
__launch_bounds__(512)
__global__ void scan16_kernel(const float* __restrict__ lut,
                              const unsigned long long* __restrict__ pcodes,
                              unsigned* __restrict__ cand_d,
                              unsigned short* __restrict__ cand_n) {
  __shared__ short sRep[32768];
  const int tid = threadIdx.x;
  const int b = blockIdx.x;

  const float4 v4 = *(const float4*)&lut[b * 2048 + tid * 4];
  float s4 = v4.x + v4.y + v4.z + v4.w;
#pragma unroll
  for (int off = 32; off > 0; off >>= 1) s4 += __shfl_xor(s4, off);
  const float mean = s4 * (1.0f / 256.0f);

  const float vals[4] = {v4.x, v4.y, v4.z, v4.w};
#pragma unroll
  for (int k2 = 0; k2 < 4; k2++) {
    float f = (vals[k2] - mean) * 64.0f;
    f = fmaxf(fminf(f, 32000.0f), -32000.0f);
    const int iv = (int)rintf(f);
    const unsigned hw = (unsigned)(unsigned short)iv;
    const unsigned wrd = hw | (hw << 16);
    const uint4 wv = make_uint4(wrd, wrd, wrd, wrd);
    const int e = tid * 4 + k2;
    *(uint4*)&((unsigned*)sRep)[e * 8] = wv;
    *(uint4*)&((unsigned*)sRep)[e * 8 + 4] = wv;
  }
  __syncthreads();

  const int r = tid & 15;
  int d0 = 0x7FFFFFFF, d1 = 0x7FFFFFFF, d2 = 0x7FFFFFFF, d3 = 0x7FFFFFFF;
  int i0 = 0, i1 = 0, i2 = 0, i3 = 0;

  unsigned long long c8 = pcodes[tid];
  for (int it = 0; it < 128; it++) {
    const int n = tid + (it << 9);
    unsigned long long nxt = 0ull;
    if (it < 127) nxt = pcodes[n + 512];
    const unsigned lo = (unsigned)c8;
    const unsigned hi = (unsigned)(c8 >> 32);
    int s;
    s  = sRep[(((lo      ) & 255u) << 4) + r        ];
    s += sRep[(((lo >>  8) & 255u) << 4) + r +  4096];
    s += sRep[(((lo >> 16) & 255u) << 4) + r +  8192];
    s += sRep[(((lo >> 24)       ) << 4) + r + 12288];
    s += sRep[(((hi      ) & 255u) << 4) + r + 16384];
    s += sRep[(((hi >>  8) & 255u) << 4) + r + 20480];
    s += sRep[(((hi >> 16) & 255u) << 4) + r + 24576];
    s += sRep[(((hi >> 24)       ) << 4) + r + 28672];
    if (s < d3) {
      if (s < d1) {
        if (s < d0) { d3 = d2; i3 = i2; d2 = d1; i2 = i1; d1 = d0; i1 = i0; d0 = s; i0 = n; }
        else        { d3 = d2; i3 = i2; d2 = d1; i2 = i1; d1 = s; i1 = n; }
      } else {
        if (s < d2) { d3 = d2; i3 = i2; d2 = s; i2 = n; }
        else        { d3 = s; i3 = n; }
      }
    }
    c8 = nxt;
  }

  const int base = b * 2048 + tid * 4;
  const uint4 dv = make_uint4((unsigned)(d0 + 0x40000000), (unsigned)(d1 + 0x40000000),
                              (unsigned)(d2 + 0x40000000), (unsigned)(d3 + 0x40000000));
  *(uint4*)&cand_d[base] = dv;
  const unsigned ni01 = (unsigned)i0 | ((unsigned)i1 << 16);
  const unsigned ni23 = (unsigned)i2 | ((unsigned)i3 << 16);
  *(uint2*)&cand_n[base] = make_uint2(ni01, ni23);
}

// ---------------- Kernel 4: SORT-FREE select + softmax + value gather --------
__launch_bounds__(256)
__global__ void select_kernel(const unsigned* __restrict__ cand_d,
                              const unsigned short* __restrict__ cand_n,
                              const int* __restrict__ value_codes,
                              const float* __restrict__ vcb,
                              const float* __restrict__ bias,
                              float* __restrict__ out) {
  __shared__ unsigned sredw[4];
  __shared__ unsigned long long clist[256];
  __shared__ float sw[256];
  __shared__ int svc[2048];
  __shared__ int scnt;
  __shared__ float sWsum;

  const int tid = threadIdx.x;
  const int b = blockIdx.x;

  const uint4 a0 = *(const uint4*)&cand_d[b * 2048 + tid * 8];
  const uint4 a1 = *(const uint4*)&cand_d[b * 2048 + tid * 8 + 4];
  const uint4 nn = *(const uint4*)&cand_n[b * 2048 + tid * 8];
  unsigned dk[8] = {a0.x, a0.y, a0.z, a0.w, a1.x, a1.y, a1.z, a1.w};
  unsigned ni[8] = {nn.x & 0xFFFFu, nn.x >> 16, nn.y & 0xFFFFu, nn.y >> 16,
                    nn.z & 0xFFFFu, nn.z >> 16, nn.w & 0xFFFFu, nn.w >> 16};

  if (tid == 0) scnt = 0;
  unsigned mn = dk[0];
#pragma unroll
  for (int j = 1; j < 8; j++) mn = (dk[j] < mn) ? dk[j] : mn;
#pragma unroll
  for (int off = 32; off > 0; off >>= 1) {
    const unsigned o = __shfl_xor(mn, off);
    mn = (o < mn) ? o : mn;
  }
  if ((tid & 63) == 0) sredw[tid >> 6] = mn;
  __syncthreads();
  unsigned sMin = sredw[0];
  sMin = (sredw[1] < sMin) ? sredw[1] : sMin;
  sMin = (sredw[2] < sMin) ? sredw[2] : sMin;
  sMin = (sredw[3] < sMin) ? sredw[3] : sMin;
  const unsigned lim = sMin + 2048u;

  const int lane = tid & 63;
  const unsigned long long lm = (1ull << lane) - 1ull;
#pragma unroll
  for (int j = 0; j < 8; j++) {
    const bool pred = dk[j] <= lim;
    const unsigned long long mask = __ballot(pred);
    int base = 0;
    if (lane == 0 && mask) base = atomicAdd(&scnt, __popcll(mask));
    base = __shfl(base, 0);
    if (pred) {
      const int pos = base + __popcll(mask & lm);
      if (pos < 256) clist[pos] = ((unsigned long long)dk[j] << 32) | ni[j];
    }
  }
  __syncthreads();
  const int cnt = min(scnt, 256);

  if (tid < cnt) {
    const int gap = (int)((unsigned)(clist[tid] >> 32)) - (int)sMin;
    sw[tid] = __expf((float)gap * -0.015625f);
  }
  for (int i = tid; i < (cnt << 3); i += 256)
    svc[i] = value_codes[((int)(clist[i >> 3] & 0xFFFFFFFFu)) * 8 + (i & 7)];
  __syncthreads();

  if (tid < 64) {
    float s = 0.f;
    for (int j = tid; j < cnt; j += 64) s += sw[j];
#pragma unroll
    for (int off = 32; off > 0; off >>= 1) s += __shfl_xor(s, off);
    if (tid == 0) sWsum = s;
  }
  __syncthreads();
  const float inv = 1.0f / sWsum;

  const int c0 = tid << 3;
  const int mv = c0 >> 8;
  const int off = c0 & 255;
  float4 acc0 = make_float4(0.f, 0.f, 0.f, 0.f);
  float4 acc1 = make_float4(0.f, 0.f, 0.f, 0.f);
  const float* vbase = vcb + mv * 65536 + off;
  for (int k = 0; k < cnt; k++) {
    const float w = sw[k];
    const float* vp = vbase + svc[(k << 3) + mv] * 256;
    const float4 v0 = *(const float4*)vp;
    const float4 v1 = *(const float4*)(vp + 4);
    acc0.x = fmaf(w, v0.x, acc0.x); acc0.y = fmaf(w, v0.y, acc0.y);
    acc0.z = fmaf(w, v0.z, acc0.z); acc0.w = fmaf(w, v0.w, acc0.w);
    acc1.x = fmaf(w, v1.x, acc1.x); acc1.y = fmaf(w, v1.y, acc1.y);
    acc1.z = fmaf(w, v1.z, acc1.z); acc1.w = fmaf(w, v1.w, acc1.w);
  }
  const float4 b0 = *(const float4*)&bias[c0];
  const float4 b1 = *(const float4*)&bias[c0 + 4];
  *(float4*)&out[b * 2048 + c0] =
      make_float4(fmaf(acc0.x, inv, b0.x), fmaf(acc0.y, inv, b0.y),
                  fmaf(acc0.z, inv, b0.z), fmaf(acc0.w, inv, b0.w));
  *(float4*)&out[b * 2048 + c0 + 4] =
      make_float4(fmaf(acc1.x, inv, b1.x), fmaf(acc1.y, inv, b1.y),
                  fmaf(acc1.z, inv, b1.z), fmaf(acc1.w, inv, b1.w));
}

// ---------------- launch ----------------
extern "C" void kernel_launch(void* const* d_in, const int* in_sizes, int n_in,
                              void* d_out, int out_size, void* d_ws, size_t ws_size,
                              hipStream_t stream) {
  const float* x    = (const float*)d_in[0];
  const float* W    = (const float*)d_in[1];
  const float* kcb  = (const float*)d_in[2];
  const float* vcb  = (const float*)d_in[3];
  const float* bias = (const float*)d_in[4];
  const int* key_codes   = (const int*)d_in[5];
  const int* value_codes = (const int*)d_in[6];
  float* out = (float*)d_out;

  // ws (25.5 MB): qpart 16MB | lut 8MB | poffs 1MB | pcodes 0.5MB.
  // cand buffers alias qpart (dead after lut; written by scan afterwards).
  float* qpart = (float*)d_ws;
  float* lut   = qpart + 4194304;
  uint4* poffs = (uint4*)(lut + 2097152);
  unsigned long long* pcodes = (unsigned long long*)(poffs + 65536);
  unsigned* cand_d = (unsigned*)d_ws;
  unsigned short* cand_n = (unsigned short*)(cand_d + 2097152);

  hipLaunchKernelGGL(gemm_q_kernel, dim3(16, 16, 5), dim3(64), 0, stream,
                     x, W, qpart, key_codes, pcodes, poffs);
  hipLaunchKernelGGL(lut_kernel, dim3(4, 16, 8), dim3(256), 0, stream,
                     qpart, kcb, lut);

  const hipError_t attr_rc = hipFuncSetAttribute(
      (const void*)scan2r_kernel, hipFuncAttributeMaxDynamicSharedMemorySize, 139264);
  if (attr_rc == hipSuccess) {
    hipLaunchKernelGGL(scan2r_kernel, dim3(512), dim3(1024), 139264, stream,
                       lut, poffs, cand_d, cand_n);
  } else {
    hipLaunchKernelGGL(scan16_kernel, dim3(1024), dim3(512), 0, stream,
                       lut, pcodes, cand_d, cand_n);
  }

  hipLaunchKernelGGL(select_kernel, dim3(1024), dim3(256), 0, stream,
                     cand_d, cand_n, value_codes, vcb, bias, out);
}